// Round 1
// baseline (192.072 us; speedup 1.0000x reference)
//
#include <hip/hip_runtime.h>

// ---------------------------------------------------------------------------
// MultiHeadedAttention  B=2, S=2048, D=1024, H=16, DK=64  (fp32 in/out)
// Pipeline: cast->bf16, QKV proj GEMMs (MFMA), flash attention, out proj GEMM
// ---------------------------------------------------------------------------

typedef __attribute__((ext_vector_type(8))) short short8;      // MFMA A/B frag (8 bf16)
typedef __attribute__((ext_vector_type(4))) float f32x4;       // MFMA C/D frag
typedef __attribute__((ext_vector_type(8))) unsigned short u16x8;

__device__ __forceinline__ unsigned short f2bf(float f) {
    unsigned int u = __builtin_bit_cast(unsigned int, f);
    u += 0x7FFFu + ((u >> 16) & 1u);          // round-to-nearest-even
    return (unsigned short)(u >> 16);
}

// ---------------------------- cast fp32 -> bf16 ----------------------------
__global__ void cast_kernel(const float* __restrict__ src,
                            unsigned short* __restrict__ dst, int n4) {
    int i = blockIdx.x * blockDim.x + threadIdx.x;
    if (i < n4) {
        float4 v = reinterpret_cast<const float4*>(src)[i];
        ushort4 o;
        o.x = f2bf(v.x); o.y = f2bf(v.y); o.z = f2bf(v.z); o.w = f2bf(v.w);
        reinterpret_cast<ushort4*>(dst)[i] = o;
    }
}

// ---------------------------------------------------------------------------
// GEMM: C[M][N] = A[M][K] * Bw[N][K]^T + bias[N]   (A,Bw bf16; acc fp32)
// 128x128 tile, BK=64, 256 threads (4 waves, each 64x64 = 4x4 frags 16x16)
// EPI: 0 = fp32 [M][N] (final out), 1 = bf16 [B,H,S,DK], 2 = bf16 [B,H,DK,S]
// ---------------------------------------------------------------------------
template<int EPI>
__global__ __launch_bounds__(256, 2)
void gemm_bt(const unsigned short* __restrict__ A,
             const unsigned short* __restrict__ Bw,
             const float* __restrict__ bias,
             void* __restrict__ Cout, int M, int N, int K)
{
    __shared__ __align__(16) unsigned short As[128][64];
    __shared__ __align__(16) unsigned short Bs[128][64];

    const int tid  = threadIdx.x;
    const int lane = tid & 63;
    const int wave = tid >> 6;
    const int wm = (wave >> 1) * 64;
    const int wn = (wave & 1) * 64;
    const int rowBase = blockIdx.y * 128;
    const int colBase = blockIdx.x * 128;
    const int l15 = lane & 15;
    const int lg  = lane >> 4;

    const int sr  = tid >> 3;   // 0..31 staging row
    const int skb = tid & 7;    // 0..7  16B chunk

    f32x4 acc[4][4] = {};

    for (int kt = 0; kt < K; kt += 64) {
        __syncthreads();
#pragma unroll
        for (int it = 0; it < 4; ++it) {
            int r = sr + it * 32;
            u16x8 va = *reinterpret_cast<const u16x8*>(A  + (size_t)(rowBase + r) * K + kt + skb * 8);
            *reinterpret_cast<u16x8*>(&As[r][(skb ^ (r & 7)) * 8]) = va;
            u16x8 vb = *reinterpret_cast<const u16x8*>(Bw + (size_t)(colBase + r) * K + kt + skb * 8);
            *reinterpret_cast<u16x8*>(&Bs[r][(skb ^ (r & 7)) * 8]) = vb;
        }
        __syncthreads();
#pragma unroll
        for (int kk = 0; kk < 2; ++kk) {
            short8 af[4], bf[4];
#pragma unroll
            for (int fm = 0; fm < 4; ++fm) {
                int r  = wm + fm * 16 + l15;
                int kb = (kk * 4 + lg) ^ (r & 7);
                af[fm] = *reinterpret_cast<const short8*>(&As[r][kb * 8]);
            }
#pragma unroll
            for (int fn = 0; fn < 4; ++fn) {
                int r  = wn + fn * 16 + l15;
                int kb = (kk * 4 + lg) ^ (r & 7);
                bf[fn] = *reinterpret_cast<const short8*>(&Bs[r][kb * 8]);
            }
#pragma unroll
            for (int fm = 0; fm < 4; ++fm)
#pragma unroll
                for (int fn = 0; fn < 4; ++fn)
                    acc[fm][fn] = __builtin_amdgcn_mfma_f32_16x16x32_bf16(
                        af[fm], bf[fn], acc[fm][fn], 0, 0, 0);
        }
    }

#pragma unroll
    for (int fm = 0; fm < 4; ++fm)
#pragma unroll
        for (int fn = 0; fn < 4; ++fn)
#pragma unroll
            for (int r = 0; r < 4; ++r) {
                int grow = rowBase + wm + fm * 16 + lg * 4 + r;   // n index
                int gcol = colBase + wn + fn * 16 + l15;          // o index
                float v = acc[fm][fn][r] + bias[gcol];
                if (EPI == 0) {
                    reinterpret_cast<float*>(Cout)[(size_t)grow * N + gcol] = v;
                } else if (EPI == 1) {        // [B,H,S,DK]
                    int b = grow >> 11, s = grow & 2047;
                    int h = gcol >> 6,  dk = gcol & 63;
                    reinterpret_cast<unsigned short*>(Cout)
                        [(((size_t)b * 16 + h) * 2048 + s) * 64 + dk] = f2bf(v);
                } else {                       // [B,H,DK,S]  (V transposed)
                    int b = grow >> 11, s = grow & 2047;
                    int h = gcol >> 6,  dk = gcol & 63;
                    reinterpret_cast<unsigned short*>(Cout)
                        [(((size_t)b * 16 + h) * 64 + dk) * 2048 + s] = f2bf(v);
                }
            }
}

// ---------------------------------------------------------------------------
// Flash attention: per block = one (b,h) x one 128-row Q tile.
// 4 waves x 32 q-rows. KV tiles of 128. Online softmax.
// Q,K: [B*H][2048][64] bf16 ; Vt: [B*H][64][2048] bf16 ; O: [B][2048][1024] bf16
// ---------------------------------------------------------------------------
__global__ __launch_bounds__(256, 2)
void attn_kernel(const unsigned short* __restrict__ Q,
                 const unsigned short* __restrict__ Kt,
                 const unsigned short* __restrict__ Vt,
                 unsigned short* __restrict__ O)
{
    __shared__ __align__(16) unsigned short Ks[128][64];
    __shared__ __align__(16) unsigned short Vs[64][128];
    __shared__ __align__(16) unsigned short Ps[128][128];

    const int bh = blockIdx.y;   // 0..31
    const int qt = blockIdx.x;   // 0..15
    const int tid  = threadIdx.x;
    const int lane = tid & 63;
    const int wave = tid >> 6;
    const int l15 = lane & 15;
    const int lg  = lane >> 4;

    const unsigned short* Qbh = Q  + (size_t)bh * 2048 * 64;
    const unsigned short* Kbh = Kt + (size_t)bh * 2048 * 64;
    const unsigned short* Vbh = Vt + (size_t)bh * 64 * 2048;

    // Q fragments kept in registers for all 16 KV tiles
    short8 qf[2][2];
#pragma unroll
    for (int fm = 0; fm < 2; ++fm)
#pragma unroll
        for (int kk = 0; kk < 2; ++kk) {
            int row = qt * 128 + wave * 32 + fm * 16 + l15;
            qf[fm][kk] = *reinterpret_cast<const short8*>(
                Qbh + (size_t)row * 64 + kk * 32 + lg * 8);
        }

    float mstate[2][4], lstate[2][4];
    f32x4 accO[2][4] = {};
#pragma unroll
    for (int fm = 0; fm < 2; ++fm)
#pragma unroll
        for (int r = 0; r < 4; ++r) { mstate[fm][r] = -1e30f; lstate[fm][r] = 0.f; }

    const int sr  = tid >> 3, skb = tid & 7;    // K staging
    const int vr  = tid >> 4, vkb = tid & 15;   // V staging

    for (int t = 0; t < 16; ++t) {
        __syncthreads();
#pragma unroll
        for (int it = 0; it < 4; ++it) {
            int r = sr + it * 32;
            u16x8 v = *reinterpret_cast<const u16x8*>(
                Kbh + (size_t)(t * 128 + r) * 64 + skb * 8);
            *reinterpret_cast<u16x8*>(&Ks[r][(skb ^ (r & 7)) * 8]) = v;
        }
#pragma unroll
        for (int it = 0; it < 4; ++it) {
            int r = vr + it * 16;
            u16x8 v = *reinterpret_cast<const u16x8*>(
                Vbh + (size_t)r * 2048 + t * 128 + vkb * 8);
            *reinterpret_cast<u16x8*>(&Vs[r][(vkb ^ (r & 15)) * 8]) = v;
        }
        __syncthreads();

        // ---- S = (Q K^T) ----
        f32x4 accS[2][8] = {};
#pragma unroll
        for (int kk = 0; kk < 2; ++kk) {
            short8 kf[8];
#pragma unroll
            for (int fn = 0; fn < 8; ++fn) {
                int r  = fn * 16 + l15;
                int kb = (kk * 4 + lg) ^ (r & 7);
                kf[fn] = *reinterpret_cast<const short8*>(&Ks[r][kb * 8]);
            }
#pragma unroll
            for (int fm = 0; fm < 2; ++fm)
#pragma unroll
                for (int fn = 0; fn < 8; ++fn)
                    accS[fm][fn] = __builtin_amdgcn_mfma_f32_16x16x32_bf16(
                        qf[fm][kk], kf[fn], accS[fm][fn], 0, 0, 0);
        }
#pragma unroll
        for (int fm = 0; fm < 2; ++fm)
#pragma unroll
            for (int fn = 0; fn < 8; ++fn)
#pragma unroll
                for (int r = 0; r < 4; ++r) accS[fm][fn][r] *= 0.125f;  // 1/sqrt(64)

        // ---- online softmax (row = wave*32 + fm*16 + lg*4 + r, cols across l15) ----
#pragma unroll
        for (int fm = 0; fm < 2; ++fm)
#pragma unroll
            for (int r = 0; r < 4; ++r) {
                float mx = -1e30f;
#pragma unroll
                for (int fn = 0; fn < 8; ++fn) mx = fmaxf(mx, accS[fm][fn][r]);
#pragma unroll
                for (int off = 1; off < 16; off <<= 1) mx = fmaxf(mx, __shfl_xor(mx, off));
                float newm = fmaxf(mstate[fm][r], mx);
                float corr = __expf(mstate[fm][r] - newm);
                mstate[fm][r] = newm;
                int row_local = wave * 32 + fm * 16 + lg * 4 + r;
                float psum = 0.f;
#pragma unroll
                for (int fn = 0; fn < 8; ++fn) {
                    float p = __expf(accS[fm][fn][r] - newm);
                    psum += p;
                    int col = fn * 16 + l15;
                    Ps[row_local][((col >> 3) ^ (row_local & 15)) * 8 + (col & 7)] = f2bf(p);
                }
#pragma unroll
                for (int off = 1; off < 16; off <<= 1) psum += __shfl_xor(psum, off);
                lstate[fm][r] = lstate[fm][r] * corr + psum;
#pragma unroll
                for (int fnv = 0; fnv < 4; ++fnv) accO[fm][fnv][r] *= corr;
            }

        // ---- O += P V   (P rows per-wave private; same-wave LDS RAW ok) ----
#pragma unroll
        for (int kkp = 0; kkp < 4; ++kkp) {
            short8 pf[2], vf[4];
#pragma unroll
            for (int fm = 0; fm < 2; ++fm) {
                int row = wave * 32 + fm * 16 + l15;
                int kb  = (kkp * 4 + lg) ^ (row & 15);
                pf[fm] = *reinterpret_cast<const short8*>(&Ps[row][kb * 8]);
            }
#pragma unroll
            for (int fnv = 0; fnv < 4; ++fnv) {
                int row = fnv * 16 + l15;
                int kb  = (kkp * 4 + lg) ^ (row & 15);
                vf[fnv] = *reinterpret_cast<const short8*>(&Vs[row][kb * 8]);
            }
#pragma unroll
            for (int fm = 0; fm < 2; ++fm)
#pragma unroll
                for (int fnv = 0; fnv < 4; ++fnv)
                    accO[fm][fnv] = __builtin_amdgcn_mfma_f32_16x16x32_bf16(
                        pf[fm], vf[fnv], accO[fm][fnv], 0, 0, 0);
        }
    }

    // ---- finalize: O[b][s][h*64+dk] ----
    const int b = bh >> 4, h = bh & 15;
#pragma unroll
    for (int fm = 0; fm < 2; ++fm)
#pragma unroll
        for (int r = 0; r < 4; ++r) {
            float inv = 1.0f / lstate[fm][r];
            int s = qt * 128 + wave * 32 + fm * 16 + lg * 4 + r;
#pragma unroll
            for (int fnv = 0; fnv < 4; ++fnv) {
                int dk = fnv * 16 + l15;
                O[((size_t)b * 2048 + s) * 1024 + h * 64 + dk] = f2bf(accO[fm][fnv][r] * inv);
            }
        }
}

// ---------------------------------------------------------------------------
extern "C" void kernel_launch(void* const* d_in, const int* in_sizes, int n_in,
                              void* d_out, int out_size, void* d_ws, size_t ws_size,
                              hipStream_t stream)
{
    const float* x  = (const float*)d_in[0];
    const float* Wq = (const float*)d_in[1];
    const float* bq = (const float*)d_in[2];
    const float* Wk = (const float*)d_in[3];
    const float* bk = (const float*)d_in[4];
    const float* Wv = (const float*)d_in[5];
    const float* bv = (const float*)d_in[6];
    const float* Wo = (const float*)d_in[7];
    const float* bo = (const float*)d_in[8];
    float* out = (float*)d_out;

    char* ws = (char*)d_ws;
    unsigned short* xb  = (unsigned short*)(ws);                        // 8 MB
    unsigned short* wqb = (unsigned short*)(ws + ((size_t)8  << 20));   // 2 MB
    unsigned short* wkb = (unsigned short*)(ws + ((size_t)10 << 20));
    unsigned short* wvb = (unsigned short*)(ws + ((size_t)12 << 20));
    unsigned short* wob = (unsigned short*)(ws + ((size_t)14 << 20));
    unsigned short* Qb  = (unsigned short*)(ws + ((size_t)16 << 20));   // 8 MB
    unsigned short* Kb  = (unsigned short*)(ws + ((size_t)24 << 20));   // 8 MB
    unsigned short* Vtb = (unsigned short*)(ws + ((size_t)32 << 20));   // 8 MB
    unsigned short* Ob  = (unsigned short*)(ws + ((size_t)40 << 20));   // 8 MB

    cast_kernel<<<(4096 * 1024 / 4) / 256, 256, 0, stream>>>(x,  xb,  4096 * 1024 / 4);
    cast_kernel<<<(1024 * 1024 / 4) / 256, 256, 0, stream>>>(Wq, wqb, 1024 * 1024 / 4);
    cast_kernel<<<(1024 * 1024 / 4) / 256, 256, 0, stream>>>(Wk, wkb, 1024 * 1024 / 4);
    cast_kernel<<<(1024 * 1024 / 4) / 256, 256, 0, stream>>>(Wv, wvb, 1024 * 1024 / 4);
    cast_kernel<<<(1024 * 1024 / 4) / 256, 256, 0, stream>>>(Wo, wob, 1024 * 1024 / 4);

    dim3 gg(8, 32);  // N/128, M/128
    gemm_bt<1><<<gg, 256, 0, stream>>>(xb, wqb, bq, Qb,  4096, 1024, 1024);
    gemm_bt<1><<<gg, 256, 0, stream>>>(xb, wkb, bk, Kb,  4096, 1024, 1024);
    gemm_bt<2><<<gg, 256, 0, stream>>>(xb, wvb, bv, Vtb, 4096, 1024, 1024);

    attn_kernel<<<dim3(16, 32), 256, 0, stream>>>(Qb, Kb, Vtb, Ob);

    gemm_bt<0><<<gg, 256, 0, stream>>>(Ob, wob, bo, out, 4096, 1024, 1024);
}

// Round 4
// 142.211 us; speedup vs baseline: 1.3506x; 1.3506x over previous
//
#include <hip/hip_runtime.h>

// ---------------------------------------------------------------------------
// MultiHeadedAttention  B=2, S=2048, D=1024, H=16, DK=64  (fp32 in/out)
// cast->bf16, fused QKV proj GEMM, flash attention (swapped QK^T), out GEMM
// Round 4: swapped-QKT kept; P-store path reverted to scalar f2bf/u16 stores
// (bisects cvt_pk + vectorized LDS store, the only unverified components).
// ---------------------------------------------------------------------------

typedef __attribute__((ext_vector_type(8))) short short8;      // MFMA A/B frag (8 bf16)
typedef __attribute__((ext_vector_type(4))) float f32x4;       // MFMA C/D frag
typedef __attribute__((ext_vector_type(8))) unsigned short u16x8;

__device__ __forceinline__ unsigned short f2bf(float f) {
    unsigned int u = __builtin_bit_cast(unsigned int, f);
    u += 0x7FFFu + ((u >> 16) & 1u);          // round-to-nearest-even
    return (unsigned short)(u >> 16);
}

// ---------------------------- cast fp32 -> bf16 ----------------------------
__global__ void cast_kernel(const float* __restrict__ src,
                            unsigned short* __restrict__ dst, int n4) {
    int i = blockIdx.x * blockDim.x + threadIdx.x;
    if (i < n4) {
        float4 v = reinterpret_cast<const float4*>(src)[i];
        ushort4 o;
        o.x = f2bf(v.x); o.y = f2bf(v.y); o.z = f2bf(v.z); o.w = f2bf(v.w);
        reinterpret_cast<ushort4*>(dst)[i] = o;
    }
}

// ---------------------------------------------------------------------------
// Fused QKV projection: z = blockIdx.z selects {Wq->Q, Wk->K, Wv->Vt}.
// C = (A[M][K] * W[N][K]^T + bias) * alpha.  M=4096, N=K=1024.
// Q epilogue folds the 1/sqrt(DK)=0.125 attention scale (exact: pow2).
// ---------------------------------------------------------------------------
__global__ __launch_bounds__(256, 2)
void qkv_gemm(const unsigned short* __restrict__ A,
              const unsigned short* __restrict__ Wq_,
              const unsigned short* __restrict__ Wk_,
              const unsigned short* __restrict__ Wv_,
              const float* __restrict__ bq_,
              const float* __restrict__ bk_,
              const float* __restrict__ bv_,
              unsigned short* __restrict__ Qb,
              unsigned short* __restrict__ Kb,
              unsigned short* __restrict__ Vtb)
{
    const int K = 1024;
    __shared__ __align__(16) unsigned short As[128][64];
    __shared__ __align__(16) unsigned short Bs[128][64];

    const int z = blockIdx.z;
    const unsigned short* Bw = (z == 0) ? Wq_ : (z == 1) ? Wk_ : Wv_;
    const float* bias = (z == 0) ? bq_ : (z == 1) ? bk_ : bv_;
    unsigned short* dst = (z == 0) ? Qb : (z == 1) ? Kb : Vtb;
    const float alpha = (z == 0) ? 0.125f : 1.0f;

    const int tid  = threadIdx.x;
    const int lane = tid & 63;
    const int wave = tid >> 6;
    const int wm = (wave >> 1) * 64;
    const int wn = (wave & 1) * 64;
    const int rowBase = blockIdx.y * 128;
    const int colBase = blockIdx.x * 128;
    const int l15 = lane & 15;
    const int lg  = lane >> 4;
    const int sr  = tid >> 3;
    const int skb = tid & 7;

    f32x4 acc[4][4] = {};

    for (int kt = 0; kt < K; kt += 64) {
        __syncthreads();
#pragma unroll
        for (int it = 0; it < 4; ++it) {
            int r = sr + it * 32;
            u16x8 va = *reinterpret_cast<const u16x8*>(A  + (size_t)(rowBase + r) * K + kt + skb * 8);
            *reinterpret_cast<u16x8*>(&As[r][(skb ^ (r & 7)) * 8]) = va;
            u16x8 vb = *reinterpret_cast<const u16x8*>(Bw + (size_t)(colBase + r) * K + kt + skb * 8);
            *reinterpret_cast<u16x8*>(&Bs[r][(skb ^ (r & 7)) * 8]) = vb;
        }
        __syncthreads();
#pragma unroll
        for (int kk = 0; kk < 2; ++kk) {
            short8 af[4], bf[4];
#pragma unroll
            for (int fm = 0; fm < 4; ++fm) {
                int r  = wm + fm * 16 + l15;
                int kb = (kk * 4 + lg) ^ (r & 7);
                af[fm] = *reinterpret_cast<const short8*>(&As[r][kb * 8]);
            }
#pragma unroll
            for (int fn = 0; fn < 4; ++fn) {
                int r  = wn + fn * 16 + l15;
                int kb = (kk * 4 + lg) ^ (r & 7);
                bf[fn] = *reinterpret_cast<const short8*>(&Bs[r][kb * 8]);
            }
#pragma unroll
            for (int fm = 0; fm < 4; ++fm)
#pragma unroll
                for (int fn = 0; fn < 4; ++fn)
                    acc[fm][fn] = __builtin_amdgcn_mfma_f32_16x16x32_bf16(
                        af[fm], bf[fn], acc[fm][fn], 0, 0, 0);
        }
    }

#pragma unroll
    for (int fm = 0; fm < 4; ++fm)
#pragma unroll
        for (int fn = 0; fn < 4; ++fn)
#pragma unroll
            for (int r = 0; r < 4; ++r) {
                int grow = rowBase + wm + fm * 16 + lg * 4 + r;
                int gcol = colBase + wn + fn * 16 + l15;
                float v = (acc[fm][fn][r] + bias[gcol]) * alpha;
                int b = grow >> 11, s = grow & 2047;
                int h = gcol >> 6,  dk = gcol & 63;
                if (z < 2)      // [B,H,S,DK]
                    dst[(((size_t)b * 16 + h) * 2048 + s) * 64 + dk] = f2bf(v);
                else            // [B,H,DK,S]  (V transposed)
                    dst[(((size_t)b * 16 + h) * 64 + dk) * 2048 + s] = f2bf(v);
            }
}

// ---------------------------------------------------------------------------
// Out-projection GEMM: out[M][N] fp32 = A[M][K]*W[N][K]^T + bias
// ---------------------------------------------------------------------------
__global__ __launch_bounds__(256, 2)
void gemm_out(const unsigned short* __restrict__ A,
              const unsigned short* __restrict__ Bw,
              const float* __restrict__ bias,
              float* __restrict__ Cout, int M, int N, int K)
{
    __shared__ __align__(16) unsigned short As[128][64];
    __shared__ __align__(16) unsigned short Bs[128][64];

    const int tid  = threadIdx.x;
    const int lane = tid & 63;
    const int wave = tid >> 6;
    const int wm = (wave >> 1) * 64;
    const int wn = (wave & 1) * 64;
    const int rowBase = blockIdx.y * 128;
    const int colBase = blockIdx.x * 128;
    const int l15 = lane & 15;
    const int lg  = lane >> 4;
    const int sr  = tid >> 3;
    const int skb = tid & 7;

    f32x4 acc[4][4] = {};

    for (int kt = 0; kt < K; kt += 64) {
        __syncthreads();
#pragma unroll
        for (int it = 0; it < 4; ++it) {
            int r = sr + it * 32;
            u16x8 va = *reinterpret_cast<const u16x8*>(A  + (size_t)(rowBase + r) * K + kt + skb * 8);
            *reinterpret_cast<u16x8*>(&As[r][(skb ^ (r & 7)) * 8]) = va;
            u16x8 vb = *reinterpret_cast<const u16x8*>(Bw + (size_t)(colBase + r) * K + kt + skb * 8);
            *reinterpret_cast<u16x8*>(&Bs[r][(skb ^ (r & 7)) * 8]) = vb;
        }
        __syncthreads();
#pragma unroll
        for (int kk = 0; kk < 2; ++kk) {
            short8 af[4], bf[4];
#pragma unroll
            for (int fm = 0; fm < 4; ++fm) {
                int r  = wm + fm * 16 + l15;
                int kb = (kk * 4 + lg) ^ (r & 7);
                af[fm] = *reinterpret_cast<const short8*>(&As[r][kb * 8]);
            }
#pragma unroll
            for (int fn = 0; fn < 4; ++fn) {
                int r  = wn + fn * 16 + l15;
                int kb = (kk * 4 + lg) ^ (r & 7);
                bf[fn] = *reinterpret_cast<const short8*>(&Bs[r][kb * 8]);
            }
#pragma unroll
            for (int fm = 0; fm < 4; ++fm)
#pragma unroll
                for (int fn = 0; fn < 4; ++fn)
                    acc[fm][fn] = __builtin_amdgcn_mfma_f32_16x16x32_bf16(
                        af[fm], bf[fn], acc[fm][fn], 0, 0, 0);
        }
    }

#pragma unroll
    for (int fm = 0; fm < 4; ++fm)
#pragma unroll
        for (int fn = 0; fn < 4; ++fn)
#pragma unroll
            for (int r = 0; r < 4; ++r) {
                int grow = rowBase + wm + fm * 16 + lg * 4 + r;
                int gcol = colBase + wn + fn * 16 + l15;
                Cout[(size_t)grow * N + gcol] = acc[fm][fn][r] + bias[gcol];
            }
}

// ---------------------------------------------------------------------------
// Flash attention, swapped QK^T.  Block = (b,h) x 128 q-rows; 4 waves x 32 q.
// Q pre-scaled by 1/sqrt(DK).  St = mfma(K,Q): lane owns q-col, 32 k in regs.
// Softmax: in-reg max/sum + 2 shfl_xor; P stored via SCALAR f2bf u16 stores
// (round-1-proven store path) into per-wave swizzled Ps; fence before PV.
// K/V global loads for tile t+1 issued before compute of tile t (T14).
// ---------------------------------------------------------------------------
__global__ __launch_bounds__(256, 2)
void attn_kernel(const unsigned short* __restrict__ Q,
                 const unsigned short* __restrict__ Kt,
                 const unsigned short* __restrict__ Vt,
                 unsigned short* __restrict__ O)
{
    __shared__ __align__(16) unsigned short Ks[128][64];
    __shared__ __align__(16) unsigned short Vs[64][128];
    __shared__ __align__(16) unsigned short Ps[4][32][128];   // per-wave private

    const int bh = blockIdx.y;   // 0..31
    const int qt = blockIdx.x;   // 0..15
    const int tid  = threadIdx.x;
    const int lane = tid & 63;
    const int w    = tid >> 6;
    const int l15 = lane & 15;
    const int lg  = lane >> 4;

    const unsigned short* Qbh = Q  + (size_t)bh * 2048 * 64;
    const unsigned short* Kbh = Kt + (size_t)bh * 2048 * 64;
    const unsigned short* Vbh = Vt + (size_t)bh * 64 * 2048;

    // Q B-fragments (kept in registers; already includes 0.125 scale)
    short8 qf[2][2];
#pragma unroll
    for (int fq = 0; fq < 2; ++fq)
#pragma unroll
        for (int kk = 0; kk < 2; ++kk) {
            int row = qt * 128 + w * 32 + fq * 16 + l15;
            qf[fq][kk] = *reinterpret_cast<const short8*>(
                Qbh + (size_t)row * 64 + kk * 32 + lg * 8);
        }

    float mst[2] = {-1e30f, -1e30f};
    float lst[2] = {0.f, 0.f};
    f32x4 accO[2][4] = {};

    const int sr  = tid >> 3, skb = tid & 7;    // K staging: 8 lanes/row
    const int vr  = tid >> 4, vkb = tid & 15;   // V staging: 16 lanes/row

    unsigned short* PsW = &Ps[w][0][0];

    // prologue: stage regs for tile 0
    u16x8 kst[4], vst[4];
#pragma unroll
    for (int it = 0; it < 4; ++it)
        kst[it] = *reinterpret_cast<const u16x8*>(Kbh + (size_t)(sr + it * 32) * 64 + skb * 8);
#pragma unroll
    for (int it = 0; it < 4; ++it)
        vst[it] = *reinterpret_cast<const u16x8*>(Vbh + (size_t)(vr + it * 16) * 2048 + vkb * 8);

    for (int t = 0; t < 16; ++t) {
        __syncthreads();                       // prev tile's LDS reads done
#pragma unroll
        for (int it = 0; it < 4; ++it) {
            int r = sr + it * 32;
            *reinterpret_cast<u16x8*>(&Ks[r][(skb ^ (r & 7)) * 8]) = kst[it];
        }
#pragma unroll
        for (int it = 0; it < 4; ++it) {
            int r = vr + it * 16;
            *reinterpret_cast<u16x8*>(&Vs[r][(vkb ^ (r & 15)) * 8]) = vst[it];
        }
        __syncthreads();

        // issue next tile's global loads NOW; they complete under compute
        if (t < 15) {
#pragma unroll
            for (int it = 0; it < 4; ++it)
                kst[it] = *reinterpret_cast<const u16x8*>(
                    Kbh + (size_t)((t + 1) * 128 + sr + it * 32) * 64 + skb * 8);
#pragma unroll
            for (int it = 0; it < 4; ++it)
                vst[it] = *reinterpret_cast<const u16x8*>(
                    Vbh + (size_t)(vr + it * 16) * 2048 + (t + 1) * 128 + vkb * 8);
        }

        // ---- St = K·Q^T : accS[fk][fq] -> S[q = fq*16+l15][k = fk*16+lg*4+r]
        f32x4 accS[8][2] = {};
#pragma unroll
        for (int kk = 0; kk < 2; ++kk) {
            short8 kf[8];
#pragma unroll
            for (int fk = 0; fk < 8; ++fk) {
                int r  = fk * 16 + l15;
                int kb = (kk * 4 + lg) ^ (r & 7);
                kf[fk] = *reinterpret_cast<const short8*>(&Ks[r][kb * 8]);
            }
#pragma unroll
            for (int fk = 0; fk < 8; ++fk)
#pragma unroll
                for (int fq = 0; fq < 2; ++fq)
                    accS[fk][fq] = __builtin_amdgcn_mfma_f32_16x16x32_bf16(
                        kf[fk], qf[fq][kk], accS[fk][fq], 0, 0, 0);
        }

        // ---- online softmax: lane owns q = fq*16+l15, 32 k-values in regs
        float corrs[2];
#pragma unroll
        for (int fq = 0; fq < 2; ++fq) {
            float mx = -1e30f;
#pragma unroll
            for (int fk = 0; fk < 8; ++fk)
#pragma unroll
                for (int r = 0; r < 4; ++r) mx = fmaxf(mx, accS[fk][fq][r]);
            mx = fmaxf(mx, __shfl_xor(mx, 16));
            mx = fmaxf(mx, __shfl_xor(mx, 32));
            float newm = fmaxf(mst[fq], mx);
            float corr = __expf(mst[fq] - newm);
            mst[fq] = newm; corrs[fq] = corr;
            const int ql = fq * 16 + l15;
            float psum = 0.f;
            // SCALAR P stores (round-1-proven path); addresses byte-identical
            // to the round-3 vector path: chunk (k>>3)^(ql&7), element k&7.
#pragma unroll
            for (int fk = 0; fk < 8; ++fk)
#pragma unroll
                for (int r = 0; r < 4; ++r) {
                    float p = __expf(accS[fk][fq][r] - newm);
                    psum += p;
                    int k = fk * 16 + lg * 4 + r;
                    PsW[ql * 128 + ((k >> 3) ^ (ql & 7)) * 8 + (k & 7)] = f2bf(p);
                }
            psum += __shfl_xor(psum, 16);
            psum += __shfl_xor(psum, 32);
            lst[fq] = lst[fq] * corr + psum;
        }

        // compile-time fence: Ps stores must not be reordered past PV loads
        asm volatile("" ::: "memory");

        // ---- rescale accO rows (corr lives in lane l15==row&15)
#pragma unroll
        for (int fq = 0; fq < 2; ++fq)
#pragma unroll
            for (int r = 0; r < 4; ++r) {
                float cq = __shfl(corrs[fq], lg * 4 + r);
#pragma unroll
                for (int fd = 0; fd < 4; ++fd) accO[fq][fd][r] *= cq;
            }

        // ---- O += P·V
#pragma unroll
        for (int kkp = 0; kkp < 4; ++kkp) {
            short8 pf[2], vf[4];
#pragma unroll
            for (int fq = 0; fq < 2; ++fq) {
                int ql = fq * 16 + l15;
                int c  = (kkp * 4 + lg) ^ (ql & 7);
                pf[fq] = *reinterpret_cast<const short8*>(
                    reinterpret_cast<char*>(PsW) + ql * 256 + c * 16);
            }
#pragma unroll
            for (int fd = 0; fd < 4; ++fd) {
                int row = fd * 16 + l15;
                int kb  = (kkp * 4 + lg) ^ (row & 15);
                vf[fd] = *reinterpret_cast<const short8*>(&Vs[row][kb * 8]);
            }
#pragma unroll
            for (int fq = 0; fq < 2; ++fq)
#pragma unroll
                for (int fd = 0; fd < 4; ++fd)
                    accO[fq][fd] = __builtin_amdgcn_mfma_f32_16x16x32_bf16(
                        pf[fq], vf[fd], accO[fq][fd], 0, 0, 0);
        }
    }

    // ---- finalize ----
    const int b = bh >> 4, h = bh & 15;
#pragma unroll
    for (int fq = 0; fq < 2; ++fq)
#pragma unroll
        for (int r = 0; r < 4; ++r) {
            float linv = 1.0f / __shfl(lst[fq], lg * 4 + r);
            int s = qt * 128 + w * 32 + fq * 16 + lg * 4 + r;
#pragma unroll
            for (int fd = 0; fd < 4; ++fd) {
                int dk = fd * 16 + l15;
                O[((size_t)b * 2048 + s) * 1024 + h * 64 + dk] = f2bf(accO[fq][fd][r] * linv);
            }
        }
}

// ---------------------------------------------------------------------------
extern "C" void kernel_launch(void* const* d_in, const int* in_sizes, int n_in,
                              void* d_out, int out_size, void* d_ws, size_t ws_size,
                              hipStream_t stream)
{
    const float* x  = (const float*)d_in[0];
    const float* Wq = (const float*)d_in[1];
    const float* bq = (const float*)d_in[2];
    const float* Wk = (const float*)d_in[3];
    const float* bk = (const float*)d_in[4];
    const float* Wv = (const float*)d_in[5];
    const float* bv = (const float*)d_in[6];
    const float* Wo = (const float*)d_in[7];
    const float* bo = (const float*)d_in[8];
    float* out = (float*)d_out;

    char* ws = (char*)d_ws;
    unsigned short* xb  = (unsigned short*)(ws);                        // 8 MB
    unsigned short* wqb = (unsigned short*)(ws + ((size_t)8  << 20));   // 2 MB
    unsigned short* wkb = (unsigned short*)(ws + ((size_t)10 << 20));
    unsigned short* wvb = (unsigned short*)(ws + ((size_t)12 << 20));
    unsigned short* wob = (unsigned short*)(ws + ((size_t)14 << 20));
    unsigned short* Qb  = (unsigned short*)(ws + ((size_t)16 << 20));   // 8 MB
    unsigned short* Kb  = (unsigned short*)(ws + ((size_t)24 << 20));   // 8 MB
    unsigned short* Vtb = (unsigned short*)(ws + ((size_t)32 << 20));   // 8 MB
    unsigned short* Ob  = (unsigned short*)(ws + ((size_t)40 << 20));   // 8 MB

    cast_kernel<<<(4096 * 1024 / 4) / 256, 256, 0, stream>>>(x,  xb,  4096 * 1024 / 4);
    cast_kernel<<<(1024 * 1024 / 4) / 256, 256, 0, stream>>>(Wq, wqb, 1024 * 1024 / 4);
    cast_kernel<<<(1024 * 1024 / 4) / 256, 256, 0, stream>>>(Wk, wkb, 1024 * 1024 / 4);
    cast_kernel<<<(1024 * 1024 / 4) / 256, 256, 0, stream>>>(Wv, wvb, 1024 * 1024 / 4);
    cast_kernel<<<(1024 * 1024 / 4) / 256, 256, 0, stream>>>(Wo, wob, 1024 * 1024 / 4);

    qkv_gemm<<<dim3(8, 32, 3), 256, 0, stream>>>(xb, wqb, wkb, wvb, bq, bk, bv,
                                                 Qb, Kb, Vtb);

    attn_kernel<<<dim3(16, 32), 256, 0, stream>>>(Qb, Kb, Vtb, Ob);

    gemm_out<<<dim3(8, 32), 256, 0, stream>>>(Ob, wob, bo, out, 4096, 1024, 1024);
}

// Round 6
// 132.913 us; speedup vs baseline: 1.4451x; 1.0700x over previous
//
#include <hip/hip_runtime.h>

// ---------------------------------------------------------------------------
// MultiHeadedAttention  B=2, S=2048, D=1024, H=16, DK=64  (fp32 in/out)
// cast->bf16 (1 kernel), fused QKV GEMM + out GEMM (global_load_lds staging),
// flash attention (swapped QK^T, exp2-domain softmax, T14 prefetch).
// ---------------------------------------------------------------------------

typedef __attribute__((ext_vector_type(8))) short short8;      // MFMA A/B frag (8 bf16)
typedef __attribute__((ext_vector_type(4))) float f32x4;       // MFMA C/D frag
typedef __attribute__((ext_vector_type(8))) unsigned short u16x8;

__device__ __forceinline__ unsigned short f2bf(float f) {
    unsigned int u = __builtin_bit_cast(unsigned int, f);
    u += 0x7FFFu + ((u >> 16) & 1u);          // round-to-nearest-even
    return (unsigned short)(u >> 16);
}

// native v_exp_f32 (exp base 2)
__device__ __forceinline__ float exp2_fast(float x) {
    return __builtin_amdgcn_exp2f(x);
}

// async global->LDS, 16B per lane: dst lane-offset = lane*16 (wave-uniform base)
__device__ __forceinline__ void gload16(const void* gsrc, void* ldst) {
    __builtin_amdgcn_global_load_lds(
        (const __attribute__((address_space(1))) unsigned int*)gsrc,
        (__attribute__((address_space(3))) unsigned int*)ldst, 16, 0, 0);
}

// ---------------------------- cast fp32 -> bf16 (all tensors, one launch) ---
__global__ void cast_all(const float* __restrict__ x,
                         const float* __restrict__ wq, const float* __restrict__ wk,
                         const float* __restrict__ wv, const float* __restrict__ wo,
                         unsigned short* __restrict__ xb,
                         unsigned short* __restrict__ wqb, unsigned short* __restrict__ wkb,
                         unsigned short* __restrict__ wvb, unsigned short* __restrict__ wob)
{
    const int z = blockIdx.y;
    const float* src; unsigned short* dst; int n4;
    if (z == 0)      { src = x;  dst = xb;  n4 = 4096 * 1024 / 4; }
    else if (z == 1) { src = wq; dst = wqb; n4 = 1024 * 1024 / 4; }
    else if (z == 2) { src = wk; dst = wkb; n4 = 1024 * 1024 / 4; }
    else if (z == 3) { src = wv; dst = wvb; n4 = 1024 * 1024 / 4; }
    else             { src = wo; dst = wob; n4 = 1024 * 1024 / 4; }
    int i = blockIdx.x * blockDim.x + threadIdx.x;
    if (i < n4) {
        float4 v = reinterpret_cast<const float4*>(src)[i];
        ushort4 o;
        o.x = f2bf(v.x); o.y = f2bf(v.y); o.z = f2bf(v.z); o.w = f2bf(v.w);
        reinterpret_cast<ushort4*>(dst)[i] = o;
    }
}

// ---------------------------------------------------------------------------
// Fused QKV projection: z = blockIdx.z selects {Wq->Q, Wk->K, Wv->Vt}.
// C = (A[M][K] * W[N][K]^T + bias) * alpha.  M=4096, N=K=1024.
// Q epilogue folds 0.125 * log2(e) (exp2-domain attention scale).
// Staging: global_load_lds 16B, source-side XOR swizzle (LDS linear dest).
// ---------------------------------------------------------------------------
__global__ __launch_bounds__(256, 2)
void qkv_gemm(const unsigned short* __restrict__ A,
              const unsigned short* __restrict__ Wq_,
              const unsigned short* __restrict__ Wk_,
              const unsigned short* __restrict__ Wv_,
              const float* __restrict__ bq_,
              const float* __restrict__ bk_,
              const float* __restrict__ bv_,
              unsigned short* __restrict__ Qb,
              unsigned short* __restrict__ Kb,
              unsigned short* __restrict__ Vtb)
{
    const int K = 1024;
    __shared__ __align__(16) unsigned short As[128][64];
    __shared__ __align__(16) unsigned short Bs[128][64];

    const int z = blockIdx.z;
    const unsigned short* Bw = (z == 0) ? Wq_ : (z == 1) ? Wk_ : Wv_;
    const float* bias = (z == 0) ? bq_ : (z == 1) ? bk_ : bv_;
    unsigned short* dst = (z == 0) ? Qb : (z == 1) ? Kb : Vtb;
    const float alpha = (z == 0) ? 0.125f * 1.44269504088896340736f : 1.0f;

    const int tid  = threadIdx.x;
    const int lane = tid & 63;
    const int wave = tid >> 6;
    const int wm = (wave >> 1) * 64;
    const int wn = (wave & 1) * 64;
    const int rowBase = blockIdx.y * 128;
    const int colBase = blockIdx.x * 128;
    const int l15 = lane & 15;
    const int lg  = lane >> 4;

    // gload staging: lane -> (row = wave*8 + it*32 + (lane>>3), chunk = lane&7)
    const int srow   = lane >> 3;          // 0..7  (== r&7 since base%8==0)
    const int schunk = lane & 7;
    const int gchunk = schunk ^ srow;      // pre-swizzled global chunk

    f32x4 acc[4][4] = {};

    for (int kt = 0; kt < K; kt += 64) {
        __syncthreads();
#pragma unroll
        for (int it = 0; it < 4; ++it) {
            int r = wave * 8 + it * 32 + srow;
            gload16(A  + (size_t)(rowBase + r) * K + kt + gchunk * 8, &As[wave * 8 + it * 32][0]);
            gload16(Bw + (size_t)(colBase + r) * K + kt + gchunk * 8, &Bs[wave * 8 + it * 32][0]);
        }
        __syncthreads();   // compiler emits vmcnt(0) drain before barrier
#pragma unroll
        for (int kk = 0; kk < 2; ++kk) {
            short8 af[4], bf[4];
#pragma unroll
            for (int fm = 0; fm < 4; ++fm) {
                int r  = wm + fm * 16 + l15;
                int kb = (kk * 4 + lg) ^ (r & 7);
                af[fm] = *reinterpret_cast<const short8*>(&As[r][kb * 8]);
            }
#pragma unroll
            for (int fn = 0; fn < 4; ++fn) {
                int r  = wn + fn * 16 + l15;
                int kb = (kk * 4 + lg) ^ (r & 7);
                bf[fn] = *reinterpret_cast<const short8*>(&Bs[r][kb * 8]);
            }
#pragma unroll
            for (int fm = 0; fm < 4; ++fm)
#pragma unroll
                for (int fn = 0; fn < 4; ++fn)
                    acc[fm][fn] = __builtin_amdgcn_mfma_f32_16x16x32_bf16(
                        af[fm], bf[fn], acc[fm][fn], 0, 0, 0);
        }
    }

#pragma unroll
    for (int fm = 0; fm < 4; ++fm)
#pragma unroll
        for (int fn = 0; fn < 4; ++fn)
#pragma unroll
            for (int r = 0; r < 4; ++r) {
                int grow = rowBase + wm + fm * 16 + lg * 4 + r;
                int gcol = colBase + wn + fn * 16 + l15;
                float v = (acc[fm][fn][r] + bias[gcol]) * alpha;
                int b = grow >> 11, s = grow & 2047;
                int h = gcol >> 6,  dk = gcol & 63;
                if (z < 2)      // [B,H,S,DK]
                    dst[(((size_t)b * 16 + h) * 2048 + s) * 64 + dk] = f2bf(v);
                else            // [B,H,DK,S]  (V transposed)
                    dst[(((size_t)b * 16 + h) * 64 + dk) * 2048 + s] = f2bf(v);
            }
}

// ---------------------------------------------------------------------------
// Out-projection GEMM: out[M][N] fp32 = A[M][K]*W[N][K]^T + bias
// ---------------------------------------------------------------------------
__global__ __launch_bounds__(256, 2)
void gemm_out(const unsigned short* __restrict__ A,
              const unsigned short* __restrict__ Bw,
              const float* __restrict__ bias,
              float* __restrict__ Cout, int M, int N, int K)
{
    __shared__ __align__(16) unsigned short As[128][64];
    __shared__ __align__(16) unsigned short Bs[128][64];

    const int tid  = threadIdx.x;
    const int lane = tid & 63;
    const int wave = tid >> 6;
    const int wm = (wave >> 1) * 64;
    const int wn = (wave & 1) * 64;
    const int rowBase = blockIdx.y * 128;
    const int colBase = blockIdx.x * 128;
    const int l15 = lane & 15;
    const int lg  = lane >> 4;

    const int srow   = lane >> 3;
    const int schunk = lane & 7;
    const int gchunk = schunk ^ srow;

    f32x4 acc[4][4] = {};

    for (int kt = 0; kt < K; kt += 64) {
        __syncthreads();
#pragma unroll
        for (int it = 0; it < 4; ++it) {
            int r = wave * 8 + it * 32 + srow;
            gload16(A  + (size_t)(rowBase + r) * K + kt + gchunk * 8, &As[wave * 8 + it * 32][0]);
            gload16(Bw + (size_t)(colBase + r) * K + kt + gchunk * 8, &Bs[wave * 8 + it * 32][0]);
        }
        __syncthreads();
#pragma unroll
        for (int kk = 0; kk < 2; ++kk) {
            short8 af[4], bf[4];
#pragma unroll
            for (int fm = 0; fm < 4; ++fm) {
                int r  = wm + fm * 16 + l15;
                int kb = (kk * 4 + lg) ^ (r & 7);
                af[fm] = *reinterpret_cast<const short8*>(&As[r][kb * 8]);
            }
#pragma unroll
            for (int fn = 0; fn < 4; ++fn) {
                int r  = wn + fn * 16 + l15;
                int kb = (kk * 4 + lg) ^ (r & 7);
                bf[fn] = *reinterpret_cast<const short8*>(&Bs[r][kb * 8]);
            }
#pragma unroll
            for (int fm = 0; fm < 4; ++fm)
#pragma unroll
                for (int fn = 0; fn < 4; ++fn)
                    acc[fm][fn] = __builtin_amdgcn_mfma_f32_16x16x32_bf16(
                        af[fm], bf[fn], acc[fm][fn], 0, 0, 0);
        }
    }

#pragma unroll
    for (int fm = 0; fm < 4; ++fm)
#pragma unroll
        for (int fn = 0; fn < 4; ++fn)
#pragma unroll
            for (int r = 0; r < 4; ++r) {
                int grow = rowBase + wm + fm * 16 + lg * 4 + r;
                int gcol = colBase + wn + fn * 16 + l15;
                Cout[(size_t)grow * N + gcol] = acc[fm][fn][r] + bias[gcol];
            }
}

// ---------------------------------------------------------------------------
// Flash attention, swapped QK^T.  Block = (b,h) x 128 q-rows; 4 waves x 32 q.
// Q pre-scaled by 0.125*log2e -> softmax in exp2 domain (one v_exp per elem).
// P stored via scalar f2bf u16 stores (proven path) into per-wave swizzled Ps.
// K/V global loads for tile t+1 issued before compute of tile t (T14).
// ---------------------------------------------------------------------------
__global__ __launch_bounds__(256, 2)
void attn_kernel(const unsigned short* __restrict__ Q,
                 const unsigned short* __restrict__ Kt,
                 const unsigned short* __restrict__ Vt,
                 unsigned short* __restrict__ O)
{
    __shared__ __align__(16) unsigned short Ks[128][64];
    __shared__ __align__(16) unsigned short Vs[64][128];
    __shared__ __align__(16) unsigned short Ps[4][32][128];   // per-wave private

    const int bh = blockIdx.y;   // 0..31
    const int qt = blockIdx.x;   // 0..15
    const int tid  = threadIdx.x;
    const int lane = tid & 63;
    const int w    = tid >> 6;
    const int l15 = lane & 15;
    const int lg  = lane >> 4;

    const unsigned short* Qbh = Q  + (size_t)bh * 2048 * 64;
    const unsigned short* Kbh = Kt + (size_t)bh * 2048 * 64;
    const unsigned short* Vbh = Vt + (size_t)bh * 64 * 2048;

    // Q B-fragments (kept in registers; already includes exp2-domain scale)
    short8 qf[2][2];
#pragma unroll
    for (int fq = 0; fq < 2; ++fq)
#pragma unroll
        for (int kk = 0; kk < 2; ++kk) {
            int row = qt * 128 + w * 32 + fq * 16 + l15;
            qf[fq][kk] = *reinterpret_cast<const short8*>(
                Qbh + (size_t)row * 64 + kk * 32 + lg * 8);
        }

    float mst[2] = {-1e30f, -1e30f};
    float lst[2] = {0.f, 0.f};
    f32x4 accO[2][4] = {};

    const int sr  = tid >> 3, skb = tid & 7;    // K staging: 8 lanes/row
    const int vr  = tid >> 4, vkb = tid & 15;   // V staging: 16 lanes/row

    unsigned short* PsW = &Ps[w][0][0];

    // prologue: stage regs for tile 0
    u16x8 kst[4], vst[4];
#pragma unroll
    for (int it = 0; it < 4; ++it)
        kst[it] = *reinterpret_cast<const u16x8*>(Kbh + (size_t)(sr + it * 32) * 64 + skb * 8);
#pragma unroll
    for (int it = 0; it < 4; ++it)
        vst[it] = *reinterpret_cast<const u16x8*>(Vbh + (size_t)(vr + it * 16) * 2048 + vkb * 8);

    for (int t = 0; t < 16; ++t) {
        __syncthreads();                       // prev tile's LDS reads done
#pragma unroll
        for (int it = 0; it < 4; ++it) {
            int r = sr + it * 32;
            *reinterpret_cast<u16x8*>(&Ks[r][(skb ^ (r & 7)) * 8]) = kst[it];
        }
#pragma unroll
        for (int it = 0; it < 4; ++it) {
            int r = vr + it * 16;
            *reinterpret_cast<u16x8*>(&Vs[r][(vkb ^ (r & 15)) * 8]) = vst[it];
        }
        __syncthreads();

        // issue next tile's global loads NOW; they complete under compute
        if (t < 15) {
#pragma unroll
            for (int it = 0; it < 4; ++it)
                kst[it] = *reinterpret_cast<const u16x8*>(
                    Kbh + (size_t)((t + 1) * 128 + sr + it * 32) * 64 + skb * 8);
#pragma unroll
            for (int it = 0; it < 4; ++it)
                vst[it] = *reinterpret_cast<const u16x8*>(
                    Vbh + (size_t)(vr + it * 16) * 2048 + (t + 1) * 128 + vkb * 8);
        }

        // ---- St = K·Q^T : accS[fk][fq] -> S[q = fq*16+l15][k = fk*16+lg*4+r]
        f32x4 accS[8][2] = {};
#pragma unroll
        for (int kk = 0; kk < 2; ++kk) {
            short8 kf[8];
#pragma unroll
            for (int fk = 0; fk < 8; ++fk) {
                int r  = fk * 16 + l15;
                int kb = (kk * 4 + lg) ^ (r & 7);
                kf[fk] = *reinterpret_cast<const short8*>(&Ks[r][kb * 8]);
            }
#pragma unroll
            for (int fk = 0; fk < 8; ++fk)
#pragma unroll
                for (int fq = 0; fq < 2; ++fq)
                    accS[fk][fq] = __builtin_amdgcn_mfma_f32_16x16x32_bf16(
                        kf[fk], qf[fq][kk], accS[fk][fq], 0, 0, 0);
        }

        // ---- online softmax (exp2 domain): lane owns q = fq*16+l15
        float corrs[2];
#pragma unroll
        for (int fq = 0; fq < 2; ++fq) {
            float mx = -1e30f;
#pragma unroll
            for (int fk = 0; fk < 8; ++fk)
#pragma unroll
                for (int r = 0; r < 4; ++r) mx = fmaxf(mx, accS[fk][fq][r]);
            mx = fmaxf(mx, __shfl_xor(mx, 16));
            mx = fmaxf(mx, __shfl_xor(mx, 32));
            float newm = fmaxf(mst[fq], mx);
            float corr = exp2_fast(mst[fq] - newm);
            mst[fq] = newm; corrs[fq] = corr;
            const int ql = fq * 16 + l15;
            float psum = 0.f;
            // SCALAR P stores (proven path): chunk (k>>3)^(ql&7), element k&7
#pragma unroll
            for (int fk = 0; fk < 8; ++fk)
#pragma unroll
                for (int r = 0; r < 4; ++r) {
                    float p = exp2_fast(accS[fk][fq][r] - newm);
                    psum += p;
                    int k = fk * 16 + lg * 4 + r;
                    PsW[ql * 128 + ((k >> 3) ^ (ql & 7)) * 8 + (k & 7)] = f2bf(p);
                }
            psum += __shfl_xor(psum, 16);
            psum += __shfl_xor(psum, 32);
            lst[fq] = lst[fq] * corr + psum;
        }

        // compile-time fence: Ps stores must not be reordered past PV loads
        asm volatile("" ::: "memory");

        // ---- rescale accO rows (corr lives in lane l15==row&15)
#pragma unroll
        for (int fq = 0; fq < 2; ++fq)
#pragma unroll
            for (int r = 0; r < 4; ++r) {
                float cq = __shfl(corrs[fq], lg * 4 + r);
#pragma unroll
                for (int fd = 0; fd < 4; ++fd) accO[fq][fd][r] *= cq;
            }

        // ---- O += P·V
#pragma unroll
        for (int kkp = 0; kkp < 4; ++kkp) {
            short8 pf[2], vf[4];
#pragma unroll
            for (int fq = 0; fq < 2; ++fq) {
                int ql = fq * 16 + l15;
                int c  = (kkp * 4 + lg) ^ (ql & 7);
                pf[fq] = *reinterpret_cast<const short8*>(
                    reinterpret_cast<char*>(PsW) + ql * 256 + c * 16);
            }
#pragma unroll
            for (int fd = 0; fd < 4; ++fd) {
                int row = fd * 16 + l15;
                int kb  = (kkp * 4 + lg) ^ (row & 15);
                vf[fd] = *reinterpret_cast<const short8*>(&Vs[row][kb * 8]);
            }
#pragma unroll
            for (int fq = 0; fq < 2; ++fq)
#pragma unroll
                for (int fd = 0; fd < 4; ++fd)
                    accO[fq][fd] = __builtin_amdgcn_mfma_f32_16x16x32_bf16(
                        pf[fq], vf[fd], accO[fq][fd], 0, 0, 0);
        }
    }

    // ---- finalize ----
    const int b = bh >> 4, h = bh & 15;
#pragma unroll
    for (int fq = 0; fq < 2; ++fq)
#pragma unroll
        for (int r = 0; r < 4; ++r) {
            float linv = 1.0f / __shfl(lst[fq], lg * 4 + r);
            int s = qt * 128 + w * 32 + fq * 16 + lg * 4 + r;
#pragma unroll
            for (int fd = 0; fd < 4; ++fd) {
                int dk = fd * 16 + l15;
                O[((size_t)b * 2048 + s) * 1024 + h * 64 + dk] = f2bf(accO[fq][fd][r] * linv);
            }
        }
}

// ---------------------------------------------------------------------------
extern "C" void kernel_launch(void* const* d_in, const int* in_sizes, int n_in,
                              void* d_out, int out_size, void* d_ws, size_t ws_size,
                              hipStream_t stream)
{
    const float* x  = (const float*)d_in[0];
    const float* Wq = (const float*)d_in[1];
    const float* bq = (const float*)d_in[2];
    const float* Wk = (const float*)d_in[3];
    const float* bk = (const float*)d_in[4];
    const float* Wv = (const float*)d_in[5];
    const float* bv = (const float*)d_in[6];
    const float* Wo = (const float*)d_in[7];
    const float* bo = (const float*)d_in[8];
    float* out = (float*)d_out;

    char* ws = (char*)d_ws;
    unsigned short* xb  = (unsigned short*)(ws);                        // 8 MB
    unsigned short* wqb = (unsigned short*)(ws + ((size_t)8  << 20));   // 2 MB
    unsigned short* wkb = (unsigned short*)(ws + ((size_t)10 << 20));
    unsigned short* wvb = (unsigned short*)(ws + ((size_t)12 << 20));
    unsigned short* wob = (unsigned short*)(ws + ((size_t)14 << 20));
    unsigned short* Qb  = (unsigned short*)(ws + ((size_t)16 << 20));   // 8 MB
    unsigned short* Kb  = (unsigned short*)(ws + ((size_t)24 << 20));   // 8 MB
    unsigned short* Vtb = (unsigned short*)(ws + ((size_t)32 << 20));   // 8 MB
    unsigned short* Ob  = (unsigned short*)(ws + ((size_t)40 << 20));   // 8 MB

    cast_all<<<dim3(4096, 5), 256, 0, stream>>>(x, Wq, Wk, Wv, Wo,
                                                xb, wqb, wkb, wvb, wob);

    qkv_gemm<<<dim3(8, 32, 3), 256, 0, stream>>>(xb, wqb, wkb, wvb, bq, bk, bv,
                                                 Qb, Kb, Vtb);

    attn_kernel<<<dim3(16, 32), 256, 0, stream>>>(Qb, Kb, Vtb, Ob);

    gemm_out<<<dim3(8, 32), 256, 0, stream>>>(Ob, wob, bo, out, 4096, 1024, 1024);
}